// Round 1
// baseline (209.242 us; speedup 1.0000x reference)
//
#include <hip/hip_runtime.h>

typedef __attribute__((ext_vector_type(8))) __bf16 bf16x8;
typedef __attribute__((ext_vector_type(4))) __bf16 bf16x4;
typedef __attribute__((ext_vector_type(4))) float f32x4;

constexpr int B = 2, SQ = 2048, SK = 2048, H = 16, D = 128;
constexpr int QBLK = 64, KVBLK = 64, NWAVES = 4;
constexpr int KPAD = 136;   // bf16 elems per Klds row (272 B: 16B-aligned, +4 bank shift/row)
constexpr int VPAD = 68;    // bf16 elems per Vtlds row (136 B: 8B-aligned, +2 bank shift/row)
constexpr int PPAD = 68;    // P staging row
constexpr float SCALE = 0.08838834764831845f;  // 1/sqrt(128)

__global__ __launch_bounds__(256, 2) void fa_fwd(
    const float* __restrict__ q, const float* __restrict__ kv,
    float* __restrict__ out)
{
  __shared__ __bf16 Klds[KVBLK * KPAD];        // [s][d]
  __shared__ __bf16 Vtlds[D * VPAD];           // [d][s]  (transposed)
  __shared__ __bf16 Plds[NWAVES * 16 * PPAD];  // per-wave P

  const int tid  = threadIdx.x;
  const int wave = tid >> 6;
  const int lane = tid & 63;
  const int l16  = lane & 15;
  const int hi   = lane >> 4;      // 0..3
  const int dbase = hi * 8;

  const int nQt = SQ / QBLK;               // 32
  const int bid = blockIdx.x;
  const int bh  = bid % (B * H);
  const int qt  = nQt - 1 - bid / (B * H); // biggest-work blocks first
  const int b   = bh / H;
  const int h   = bh % H;

  const int q0 = qt * QBLK + wave * 16;    // wave's first Q row

  // ---- Q fragments (scaled, bf16), row = l16, d = kk*32 + dbase + j ----
  const float* Qg = q + (((size_t)b * SQ + q0 + l16) * H + h) * D;
  bf16x8 qf[4];
  #pragma unroll
  for (int kk = 0; kk < 4; ++kk) {
    const float4 a = *(const float4*)(Qg + kk * 32 + dbase);
    const float4 c = *(const float4*)(Qg + kk * 32 + dbase + 4);
    qf[kk][0] = (__bf16)(a.x * SCALE); qf[kk][1] = (__bf16)(a.y * SCALE);
    qf[kk][2] = (__bf16)(a.z * SCALE); qf[kk][3] = (__bf16)(a.w * SCALE);
    qf[kk][4] = (__bf16)(c.x * SCALE); qf[kk][5] = (__bf16)(c.y * SCALE);
    qf[kk][6] = (__bf16)(c.z * SCALE); qf[kk][7] = (__bf16)(c.w * SCALE);
  }

  f32x4 o[8];
  #pragma unroll
  for (int nd = 0; nd < 8; ++nd) o[nd] = (f32x4){0.f, 0.f, 0.f, 0.f};
  float m_run[4] = {-1e30f, -1e30f, -1e30f, -1e30f};
  float l_run[4] = {0.f, 0.f, 0.f, 0.f};

  const float* Kg0 = kv + (((size_t)b * SK * 2 + 0) * H + h) * D;
  const float* Vg0 = kv + (((size_t)b * SK * 2 + 1) * H + h) * D;
  const int RS = 2 * H * D;   // kv row stride in floats (s -> s+1)

  const int nT = qt + 1;
  for (int t = 0; t < nT; ++t) {
    const int s0 = t * KVBLK;
    __syncthreads();   // previous tile fully consumed before overwrite

    // ---- stage K [64][136] and V^T [128][68] (f32 -> bf16) ----
    #pragma unroll
    for (int i = 0; i < 8; ++i) {
      int idx = tid + i * 256;        // 0..2047
      int row = idx >> 5;             // 0..63
      int c4  = (idx & 31) * 4;       // 0..124
      {
        const float4 f = *(const float4*)(Kg0 + (size_t)(s0 + row) * RS + c4);
        bf16x4 w; w[0] = (__bf16)f.x; w[1] = (__bf16)f.y;
                  w[2] = (__bf16)f.z; w[3] = (__bf16)f.w;
        *(bf16x4*)&Klds[row * KPAD + c4] = w;
      }
      {
        const float4 f = *(const float4*)(Vg0 + (size_t)(s0 + row) * RS + c4);
        Vtlds[(c4 + 0) * VPAD + row] = (__bf16)f.x;
        Vtlds[(c4 + 1) * VPAD + row] = (__bf16)f.y;
        Vtlds[(c4 + 2) * VPAD + row] = (__bf16)f.z;
        Vtlds[(c4 + 3) * VPAD + row] = (__bf16)f.w;
      }
    }
    __syncthreads();

    // ---- QK^T: sacc[n][r] = S[q0 + hi*4+r][s0 + n*16 + l16] ----
    f32x4 sacc[4];
    #pragma unroll
    for (int n = 0; n < 4; ++n) sacc[n] = (f32x4){0.f, 0.f, 0.f, 0.f};
    #pragma unroll
    for (int n = 0; n < 4; ++n) {
      #pragma unroll
      for (int kk = 0; kk < 4; ++kk) {
        bf16x8 kf = *(const bf16x8*)&Klds[(n * 16 + l16) * KPAD + kk * 32 + dbase];
        sacc[n] = __builtin_amdgcn_mfma_f32_16x16x32_bf16(qf[kk], kf, sacc[n], 0, 0, 0);
      }
    }

    // ---- causal mask (diagonal tile only) ----
    if (s0 + KVBLK - 1 > q0) {
      #pragma unroll
      for (int n = 0; n < 4; ++n) {
        int s = s0 + n * 16 + l16;
        #pragma unroll
        for (int r = 0; r < 4; ++r) {
          int trow = q0 + hi * 4 + r;
          if (s > trow) sacc[n][r] = -10000.0f;
        }
      }
    }

    // ---- wave-parallel online softmax (rows live in 16-lane groups) ----
    float mt[4];
    #pragma unroll
    for (int r = 0; r < 4; ++r)
      mt[r] = fmaxf(fmaxf(sacc[0][r], sacc[1][r]), fmaxf(sacc[2][r], sacc[3][r]));
    #pragma unroll
    for (int dlt = 1; dlt < 16; dlt <<= 1) {
      #pragma unroll
      for (int r = 0; r < 4; ++r)
        mt[r] = fmaxf(mt[r], __shfl_xor(mt[r], dlt));
    }

    float alpha[4], rsum[4];
    #pragma unroll
    for (int r = 0; r < 4; ++r) {
      float mnew = fmaxf(m_run[r], mt[r]);
      alpha[r] = __expf(m_run[r] - mnew);
      m_run[r] = mnew;
      float acc = 0.f;
      #pragma unroll
      for (int n = 0; n < 4; ++n) {
        float p = __expf(sacc[n][r] - mnew);
        sacc[n][r] = p;
        acc += p;
      }
      rsum[r] = acc;
    }
    #pragma unroll
    for (int dlt = 1; dlt < 16; dlt <<= 1) {
      #pragma unroll
      for (int r = 0; r < 4; ++r)
        rsum[r] += __shfl_xor(rsum[r], dlt);
    }
    #pragma unroll
    for (int r = 0; r < 4; ++r)
      l_run[r] = l_run[r] * alpha[r] + rsum[r];
    #pragma unroll
    for (int nd = 0; nd < 8; ++nd) {
      #pragma unroll
      for (int r = 0; r < 4; ++r) o[nd][r] *= alpha[r];
    }

    // ---- P (bf16) to per-wave LDS, C-layout -> A-layout ----
    __bf16* Pw = &Plds[wave * 16 * PPAD];
    #pragma unroll
    for (int n = 0; n < 4; ++n) {
      #pragma unroll
      for (int r = 0; r < 4; ++r)
        Pw[(hi * 4 + r) * PPAD + n * 16 + l16] = (__bf16)sacc[n][r];
    }

    // ---- PV: o[nd] += P[16x64] * V[64 x 16(nd)] ----
    #pragma unroll
    for (int kk2 = 0; kk2 < 2; ++kk2) {
      const __bf16* pp = &Pw[l16 * PPAD + kk2 * 32 + dbase];
      bf16x4 p0 = *(const bf16x4*)pp;
      bf16x4 p1 = *(const bf16x4*)(pp + 4);
      bf16x8 pa;
      #pragma unroll
      for (int j = 0; j < 4; ++j) { pa[j] = p0[j]; pa[4 + j] = p1[j]; }
      #pragma unroll
      for (int nd = 0; nd < 8; ++nd) {
        const __bf16* vp = &Vtlds[(nd * 16 + l16) * VPAD + kk2 * 32 + dbase];
        bf16x4 v0 = *(const bf16x4*)vp;
        bf16x4 v1 = *(const bf16x4*)(vp + 4);
        bf16x8 vb;
        #pragma unroll
        for (int j = 0; j < 4; ++j) { vb[j] = v0[j]; vb[4 + j] = v1[j]; }
        o[nd] = __builtin_amdgcn_mfma_f32_16x16x32_bf16(pa, vb, o[nd], 0, 0, 0);
      }
    }
  }

  // ---- epilogue: O / l ----
  float inv[4];
  #pragma unroll
  for (int r = 0; r < 4; ++r) inv[r] = 1.0f / l_run[r];
  #pragma unroll
  for (int r = 0; r < 4; ++r) {
    float* Og = out + (((size_t)b * SQ + q0 + hi * 4 + r) * H + h) * D;
    #pragma unroll
    for (int nd = 0; nd < 8; ++nd)
      Og[nd * 16 + l16] = o[nd][r] * inv[r];
  }
}

extern "C" void kernel_launch(void* const* d_in, const int* in_sizes, int n_in,
                              void* d_out, int out_size, void* d_ws, size_t ws_size,
                              hipStream_t stream) {
  const float* q  = (const float*)d_in[0];
  const float* kv = (const float*)d_in[1];
  float* out = (float*)d_out;
  dim3 grid(B * H * (SQ / QBLK));   // 1024
  dim3 block(256);
  fa_fwd<<<grid, block, 0, stream>>>(q, kv, out);
}